// Round 9
// baseline (26.837 us; speedup 1.0000x reference)
//
#include <hip/hip_runtime.h>

// Problem constants (fixed by setup_inputs)
#define K   19
#define C   256
#define HF  64
#define WF  128
#define HW  (HF * WF)
#define BB  4
#define HL  512
#define WL  1024

// f32 near-tie threshold: f32 distance error bound < ~1e-3; pixels whose
// top-2 f32 gap < TAU get an exact f64 recompute (cooperative, see epilogue).
#define TAU 0.015f

// Block = 512 threads = 8 waves, 64 pixels (lane = pixel), wave wv covers
// channels [wv*32, wv*32+32). Identical to R8 except ONE change: the f[32]
// feature preload is pinned into VGPRs with opaque empty asm, preventing the
// compiler from rematerializing the global loads inside the k-loop (R4-R8
// profile: VGPR_Count=36 < the ~45 needed to hold f[32] -> loads were being
// re-issued per k, VALUBusy pinned at ~20%).
__global__ __launch_bounds__(512, 4) void centroid_mask_kernel(
    const float* __restrict__ feat0,   // feature_s2t
    const float* __restrict__ feat1,   // feature_target
    const float* __restrict__ cent0,   // centroids for map 0 (centroid_target)
    const float* __restrict__ cent1,   // centroids for map 1 (centroid_s2t)
    int* __restrict__ out)             // [2][BB][HL][WL] int32
{
    __shared__ float  part[8 * K * 64];  // [wv][k][pix], pix stride 1: conflict-free
    __shared__ double c2p[K][8];         // exact ||c||^2 partials
    __shared__ double sc2d[K];           // exact ||c||^2 (f64)
    __shared__ float  sc2f[K];           // rounded-exact ||c||^2 (f32)

    const int map = blockIdx.y;
    const float* __restrict__ feat = (map == 0) ? feat0 : feat1;
    const float* __restrict__ cent = (map == 0) ? cent0 : cent1;

    const int tid  = threadIdx.x;
    const int lane = tid & 63;
    const int wv   = __builtin_amdgcn_readfirstlane(tid >> 6);   // 0..7, uniform

    // ---- exact ||c_k||^2 partials (f64), 152 threads, overlaps with preload ----
    if (tid < K * 8) {
        const int k = tid >> 3, sl = tid & 7;
        const float* cp = cent + k * C + sl * 32;
        double s = 0.0;
        #pragma unroll
        for (int j = 0; j < 32; ++j) { double v = (double)cp[j]; s = fma(v, v, s); }
        c2p[k][sl] = s;
    }

    // ---- preload this wave's 32 feature channels for pixel = lane ----
    const int p  = blockIdx.x * 64 + lane;     // pixel in [0, 32768)
    const int hw = p & (HW - 1);
    const int b  = p >> 13;
    const int cbase = wv * 32;

    const float* __restrict__ fp = feat + (size_t)b * C * HW + (size_t)cbase * HW + hw;
    float f[32];
    #pragma unroll
    for (int i = 0; i < 32; ++i) f[i] = fp[(size_t)i * HW];
    // Opaque def: compiler can no longer rematerialize f[i] from its load ->
    // all 32 values MUST live in VGPRs across the k-loop (zero VMEM inside).
    #pragma unroll
    for (int i = 0; i < 32; ++i) asm volatile("" : "+v"(f[i]));

    // k-outer: per k, cent[k][cbase..cbase+32) = 32 consecutive dwords at a
    // wave-uniform address (scalar-load eligible, L2-resident).
    float* __restrict__ pw = &part[(wv * K) * 64 + lane];
    #pragma unroll
    for (int k = 0; k < K; ++k) {
        const float* __restrict__ ck = cent + (size_t)k * C + cbase;
        float a0 = 0.f, a1 = 0.f, a2 = 0.f, a3 = 0.f;
        #pragma unroll
        for (int j = 0; j < 8; ++j) {
            a0 = fmaf(f[4*j+0], ck[4*j+0], a0);
            a1 = fmaf(f[4*j+1], ck[4*j+1], a1);
            a2 = fmaf(f[4*j+2], ck[4*j+2], a2);
            a3 = fmaf(f[4*j+3], ck[4*j+3], a3);
        }
        pw[k * 64] = (a0 + a1) + (a2 + a3);   // ds_write_b32, lane-contiguous
    }
    __syncthreads();

    if (tid < K) {
        double s = 0.0;
        #pragma unroll
        for (int j = 0; j < 8; ++j) s += c2p[tid][j];
        sc2d[tid] = s;
        sc2f[tid] = (float)s;
    }
    __syncthreads();

    // ---- epilogue: wave 0, lane = pixel ----
    if (tid < 64) {
        const int pix = tid;
        float d[K];
        #pragma unroll
        for (int k = 0; k < K; ++k) {
            float s = 0.f;
            #pragma unroll
            for (int w8 = 0; w8 < 8; ++w8)
                s += part[(w8 * K + k) * 64 + pix];
            d[k] = sc2f[k] - 2.0f * s;
        }
        int best = 0; float m1 = d[0];
        #pragma unroll
        for (int k = 1; k < K; ++k) if (d[k] < m1) { m1 = d[k]; best = k; }

        // near-tie candidates within TAU of the f32 min (always includes best)
        unsigned cmask = 0u;
        #pragma unroll
        for (int k = 0; k < K; ++k) if (d[k] - m1 < TAU) cmask |= (1u << k);

        // ---- cooperative exact-f64 resolve of flagged pixels ----
        const bool need = (cmask & (cmask - 1)) != 0u;
        unsigned long long ball = __ballot(need);
        while (ball) {
            const int px = (int)__builtin_ctzll(ball);   // lowest flagged lane
            ball &= ball - 1;
            const unsigned pm  = __shfl(cmask, px, 64);
            const int      phw = __shfl(hw,    px, 64);
            const int      pb  = __shfl(b,     px, 64);
            const float* __restrict__ fcol = feat + (size_t)pb * C * HW + phw;

            // lane covers channels 4*lane .. 4*lane+3
            const int c0 = tid << 2;
            double pf[4];
            #pragma unroll
            for (int j = 0; j < 4; ++j)
                pf[j] = (double)fcol[(size_t)(c0 + j) * HW];

            double bd = 1e300; int bi = 0;
            unsigned mm = pm;
            while (mm) {                      // ascending k, strict < tie-break
                const int k = (int)__builtin_ctz(mm);
                mm &= mm - 1;
                const float* __restrict__ ck = cent + (size_t)k * C + c0;
                double s = 0.0;
                #pragma unroll
                for (int j = 0; j < 4; ++j)
                    s = fma(pf[j], (double)ck[j], s);
                #pragma unroll
                for (int off = 1; off < 64; off <<= 1)
                    s += __shfl_xor(s, off, 64);
                const double dk = sc2d[k] - 2.0 * s;
                if (dk < bd) { bd = dk; bi = k; }
            }
            if (tid == px) best = bi;         // all lanes agree on bi
        }

        // write the 8x8 nearest-upsampled block
        const int w = hw & (WF - 1);
        const int h = hw >> 7;
        int4 v = make_int4(best, best, best, best);
        int* __restrict__ ob = out + (size_t)map * (BB * HL * WL)
                                   + (size_t)b * (HL * WL)
                                   + (size_t)(h * 8) * WL + (size_t)(w * 8);
        #pragma unroll
        for (int r = 0; r < 8; ++r) {
            *(int4*)(ob + (size_t)r * WL)     = v;
            *(int4*)(ob + (size_t)r * WL + 4) = v;
        }
    }
}

extern "C" void kernel_launch(void* const* d_in, const int* in_sizes, int n_in,
                              void* d_out, int out_size, void* d_ws, size_t ws_size,
                              hipStream_t stream) {
    const float* feature_s2t     = (const float*)d_in[0];
    const float* feature_target  = (const float*)d_in[1];
    // d_in[2], d_in[3]: labels — only shapes matter, unused
    const float* centroid_s2t    = (const float*)d_in[4];
    const float* centroid_target = (const float*)d_in[5];
    int* out = (int*)d_out;

    dim3 grid(32768 / 64, 2);   // (512, 2) -> 1024 blocks
    dim3 block(512);
    hipLaunchKernelGGL(centroid_mask_kernel, grid, block, 0, stream,
                       feature_s2t, feature_target,
                       centroid_target, centroid_s2t, out);
}